// Round 5
// baseline (425.414 us; speedup 1.0000x reference)
//
#include <hip/hip_runtime.h>
#include <hip/hip_bf16.h>
#include <math.h>

typedef __attribute__((ext_vector_type(4))) float f32x4;
typedef __attribute__((ext_vector_type(8))) __bf16 bf16x8;
typedef unsigned short u16;

#define L2E 1.44269504088896f

__device__ __forceinline__ u16 f2b(float f) {
  union { float f; unsigned u; } x; x.f = f;
  unsigned r = x.u + 0x7fffu + ((x.u >> 16) & 1u);
  return (u16)(r >> 16);
}

__device__ __forceinline__ void gl_lds16(const void* g, void* l) {
  __builtin_amdgcn_global_load_lds(
      (const __attribute__((address_space(1))) void*)g,
      (__attribute__((address_space(3))) void*)l, 16, 0, 0);
}

// ---------------------------------------------------------------------------
// GEMM: C[M,N] = A[M,K] (bf16, lda) * Bt[N,K]^T (bf16) + bias[N]
// EPI: 0 = bf16 store, 1 = gelu(exact)+bf16, 2 = fp32 store,
//      3 = transposed V store into Vt[(b*16+h)*64+d][2048] (bf16)
// BN: 128 (2 B-tiles staged) or 64 (1 B-tile; for N=1024 shapes -> 512 blocks)
// SPLITK: 2 -> blockIdx.z==0 writes C (+bias), z==1 writes C2 (no bias).
// ---------------------------------------------------------------------------
template<int EPI, int BN, int SPLITK>
__global__ __launch_bounds__(256, 3)
void gemm_bt(const u16* __restrict__ A, int lda,
             const u16* __restrict__ Bt,
             const float* __restrict__ bias,
             void* __restrict__ C, void* __restrict__ C2, int ldc,
             int M, int N, int K)
{
  constexpr int NF = BN / 32;  // n-frags per wave
  __shared__ u16 As[128 * 32];
  __shared__ u16 Bs[BN * 32];
  const int t = threadIdx.x;
  const int lane = t & 63;
  const int w = t >> 6;
  const int wr = w >> 1, wc = w & 1;
  const int row0 = blockIdx.y * 128, col0 = blockIdx.x * BN;
  const int r = lane & 15, g = lane >> 4;

  f32x4 acc[4][NF];
#pragma unroll
  for (int m = 0; m < 4; ++m)
#pragma unroll
    for (int n = 0; n < NF; ++n) acc[m][n] = (f32x4){0.f, 0.f, 0.f, 0.f};

  const int KS = K / SPLITK;
  const int kbeg = (SPLITK > 1) ? blockIdx.z * KS : 0;

  const u16* Ag = A + (size_t)(row0 + (t >> 2)) * lda + (t & 3) * 8 + kbeg;
  const u16* Bg = Bt + (size_t)(col0 + (t >> 2)) * K + (t & 3) * 8 + kbeg;
  u16* Asw  = &As[t * 8];
  u16* Asw2 = &As[(t + 256) * 8];
  u16* Bsw  = &Bs[t * 8];
  u16* Bsw2 = (BN == 128) ? &Bs[(t + 256) * 8] : nullptr;
  const size_t a2 = (size_t)64 * lda, bo2 = (size_t)64 * K;

  for (int kt = 0; kt < KS; kt += 32) {
    gl_lds16(Ag + kt, Asw);
    gl_lds16(Ag + a2 + kt, Asw2);
    gl_lds16(Bg + kt, Bsw);
    if constexpr (BN == 128) gl_lds16(Bg + bo2 + kt, Bsw2);
    __syncthreads();
    bf16x8 af[4], bfr[NF];
#pragma unroll
    for (int m = 0; m < 4; ++m)
      af[m] = *(const bf16x8*)&As[(wr * 64 + m * 16 + r) * 32 + g * 8];
#pragma unroll
    for (int n = 0; n < NF; ++n)
      bfr[n] = *(const bf16x8*)&Bs[(wc * (BN / 2) + n * 16 + r) * 32 + g * 8];
#pragma unroll
    for (int m = 0; m < 4; ++m)
#pragma unroll
      for (int n = 0; n < NF; ++n)
        acc[m][n] = __builtin_amdgcn_mfma_f32_16x16x32_bf16(af[m], bfr[n], acc[m][n], 0, 0, 0);
    __syncthreads();
  }

  bool addb = true;
  float* Cf = (float*)C;
  if constexpr (SPLITK > 1) {
    if (blockIdx.z != 0) { addb = false; Cf = (float*)C2; }
  }

#pragma unroll
  for (int n = 0; n < NF; ++n) {
    const int col = col0 + wc * (BN / 2) + n * 16 + r;
    const float bv = addb ? bias[col] : 0.f;
#pragma unroll
    for (int m = 0; m < 4; ++m) {
      const int rb = row0 + wr * 64 + m * 16 + g * 4;
      if constexpr (EPI == 3) {
        const int b_ = rb >> 11, nn = rb & 2047;
        const int h_ = col >> 6, d_ = col & 63;
        u16* vp = (u16*)C + ((size_t)((b_ * 16 + h_) * 64 + d_)) * 2048 + nn;
        ushort4 pk;
        pk.x = f2b(acc[m][n][0] + bv);
        pk.y = f2b(acc[m][n][1] + bv);
        pk.z = f2b(acc[m][n][2] + bv);
        pk.w = f2b(acc[m][n][3] + bv);
        *(ushort4*)vp = pk;
      } else {
#pragma unroll
        for (int j = 0; j < 4; ++j) {
          float v = acc[m][n][j] + bv;
          if constexpr (EPI == 1) v = 0.5f * v * (1.0f + erff(v * 0.70710678118654752f));
          const size_t idx = (size_t)(rb + j) * ldc + col;
          if constexpr (EPI == 2) Cf[idx] = v;
          else ((u16*)C)[idx] = f2b(v);
        }
      }
    }
  }
}

// ---------------------------------------------------------------------------
// Flash attention v3: QBLK=32 (2-wave / 128-thread blocks), KVBLK=64.
// Grid (32 bh, 64 q-tiles) = 2048 blocks -> 8 blocks/CU (LDS 20KB).
// Max-free softmax (|QK/8|+|bias| bounded => exp<=~e^10, fp32-safe).
// Q pre-scaled by 0.125*log2e; bias*log2e = MFMA C-init, REGISTER-PREFETCHED
// one tile ahead (loads issue during tile t's exp/PV phase).
// s_setprio(1) around MFMA clusters (m191: +4-7% attn).
// ---------------------------------------------------------------------------
__global__ __launch_bounds__(128, 4)
void attn_kernel(const u16* __restrict__ Qg,   // [4096][1536], cols 0..1023 = Q
                 const u16* __restrict__ Kg,   // [4096][1024]
                 const u16* __restrict__ Vt,   // [(b*16+h)*64+d][2048]
                 const float* __restrict__ Bf, // [2048][2048] fp32 bias
                 u16* __restrict__ O)          // [4096][1024]
{
  const int bh = blockIdx.x;
  const int b = bh >> 4, h = bh & 15;
  const int q0 = blockIdx.y * 32;
  const int t = threadIdx.x;            // 0..127
  const int lane = t & 63;
  const int w = t >> 6;                 // 0..1
  const int r = lane & 15, g = lane >> 4;

  __shared__ u16 Ks[64 * 64];           // 8 KB: K tile [m][d]
  __shared__ u16 Vs[64 * 64];           // 8 KB: V^T tile [d][m]
  __shared__ __bf16 Ps[2][16 * 64];     // 4 KB: per-wave P

  // Q fragments, scaled by 0.125*log2e
  bf16x8 qa[2];
  {
    const size_t qrow = (size_t)(b * 2048 + q0 + w * 16 + r);
    const u16* qp = Qg + qrow * 1536 + h * 64 + g * 8;
    qa[0] = *(const bf16x8*)qp;
    qa[1] = *(const bf16x8*)(qp + 32);
#pragma unroll
    for (int dh = 0; dh < 2; ++dh)
#pragma unroll
      for (int i = 0; i < 8; ++i)
        qa[dh][i] = (__bf16)((float)qa[dh][i] * (0.125f * L2E));
  }

  f32x4 Oa[4];
#pragma unroll
  for (int dc = 0; dc < 4; ++dc) Oa[dc] = (f32x4){0.f, 0.f, 0.f, 0.f};
  float lsum[4] = {0.f, 0.f, 0.f, 0.f};

  // staging geometry: 512 16B-segs per tile (K) resp (V); 4 per thread each
  int srw[4], ssg[4];
#pragma unroll
  for (int i = 0; i < 4; ++i) {
    const int s_ = i * 128 + t;
    srw[i] = s_ >> 3;
    ssg[i] = (s_ & 7) ^ (srw[i] & 7);
  }
  const u16* Kb4[4];
  const u16* Vb4[4];
#pragma unroll
  for (int i = 0; i < 4; ++i) {
    Kb4[i] = Kg + (size_t)(b * 2048 + srw[i]) * 1024 + h * 64 + ssg[i] * 8;
    Vb4[i] = Vt + (size_t)(bh * 64 + srw[i]) * 2048 + ssg[i] * 8;
  }

  const float* bp = Bf + (size_t)(q0 + w * 16 + g * 4) * 2048 + r;

  // prefetch bias tile 0
  float bn[4][4];
#pragma unroll
  for (int mc = 0; mc < 4; ++mc)
#pragma unroll
    for (int j = 0; j < 4; ++j)
      bn[mc][j] = bp[(size_t)j * 2048 + mc * 16];

  for (int mt = 0; mt < 32; ++mt) {
    const int m0 = mt * 64;
#pragma unroll
    for (int i = 0; i < 4; ++i) {
      gl_lds16(Kb4[i] + (size_t)m0 * 1024, &Ks[(i * 128 + t) * 8]);
      gl_lds16(Vb4[i] + m0, &Vs[(i * 128 + t) * 8]);
    }

    f32x4 s[4];
#pragma unroll
    for (int mc = 0; mc < 4; ++mc)
#pragma unroll
      for (int j = 0; j < 4; ++j)
        s[mc][j] = bn[mc][j] * L2E;

    __syncthreads();

    // S = log2e*(Q K^T / 8 + bias)   [16 q x 64 m] per wave
    __builtin_amdgcn_s_setprio(1);
#pragma unroll
    for (int mc = 0; mc < 4; ++mc) {
      const int mrow = mc * 16 + r;
      const bf16x8 kb0 = *(const bf16x8*)&Ks[mrow * 64 + (((0 * 4 + g) ^ (mrow & 7)) * 8)];
      const bf16x8 kb1 = *(const bf16x8*)&Ks[mrow * 64 + (((1 * 4 + g) ^ (mrow & 7)) * 8)];
      s[mc] = __builtin_amdgcn_mfma_f32_16x16x32_bf16(qa[0], kb0, s[mc], 0, 0, 0);
      s[mc] = __builtin_amdgcn_mfma_f32_16x16x32_bf16(qa[1], kb1, s[mc], 0, 0, 0);
    }
    __builtin_amdgcn_s_setprio(0);

    // prefetch next tile's bias (latency hidden under exp + PV)
    if (mt < 31) {
#pragma unroll
      for (int mc = 0; mc < 4; ++mc)
#pragma unroll
        for (int j = 0; j < 4; ++j)
          bn[mc][j] = bp[(size_t)j * 2048 + (m0 + 64) + mc * 16];
    }

    // p = 2^s ; unnormalized row-sums; stash P (bf16) in wave-local LDS
    __bf16* pw = (__bf16*)Ps[w];
#pragma unroll
    for (int mc = 0; mc < 4; ++mc) {
      const int mm = mc * 16 + r;
#pragma unroll
      for (int j = 0; j < 4; ++j) {
        const float p = __builtin_amdgcn_exp2f(s[mc][j]);
        lsum[j] += p;
        const int qr = g * 4 + j;
        pw[qr * 64 + (((mm >> 3) ^ (qr & 7)) * 8) + (mm & 7)] = (__bf16)p;
      }
    }

    // PV: O[16 q x 64 d] += P[16 x 64] * V[64 x 64]  (wave-local P)
    const bf16x8 pa0 = *(const bf16x8*)&pw[r * 64 + (((0 * 4 + g) ^ (r & 7)) * 8)];
    const bf16x8 pa1 = *(const bf16x8*)&pw[r * 64 + (((1 * 4 + g) ^ (r & 7)) * 8)];
    __builtin_amdgcn_s_setprio(1);
#pragma unroll
    for (int dc = 0; dc < 4; ++dc) {
      const int drow = dc * 16 + r;
      const bf16x8 vb0 = *(const bf16x8*)&Vs[drow * 64 + (((0 * 4 + g) ^ (drow & 7)) * 8)];
      const bf16x8 vb1 = *(const bf16x8*)&Vs[drow * 64 + (((1 * 4 + g) ^ (drow & 7)) * 8)];
      Oa[dc] = __builtin_amdgcn_mfma_f32_16x16x32_bf16(pa0, vb0, Oa[dc], 0, 0, 0);
      Oa[dc] = __builtin_amdgcn_mfma_f32_16x16x32_bf16(pa1, vb1, Oa[dc], 0, 0, 0);
    }
    __builtin_amdgcn_s_setprio(0);
    __syncthreads();
  }

  // row-sum reduction within 16-lane groups (same g-group shares q-rows)
#pragma unroll
  for (int off = 1; off < 16; off <<= 1)
#pragma unroll
    for (int j = 0; j < 4; ++j) lsum[j] += __shfl_xor(lsum[j], off);

  u16* Os = Ks;  // reuse (past final barrier)
#pragma unroll
  for (int j = 0; j < 4; ++j) {
    const float inv = 1.0f / lsum[j];
    const int qr = w * 16 + g * 4 + j;
#pragma unroll
    for (int dc = 0; dc < 4; ++dc)
      Os[qr * 64 + dc * 16 + r] = f2b(Oa[dc][j] * inv);
  }
  __syncthreads();
#pragma unroll
  for (int i = 0; i < 2; ++i) {
    const int tt = t + i * 128;
    const int orow = tt >> 3, oseg = tt & 7;
    const uint4 v = *(const uint4*)&Os[orow * 64 + oseg * 8];
    *(uint4*)&O[(size_t)(b * 2048 + q0 + orow) * 1024 + h * 64 + oseg * 8] = v;
  }
}

// ---------------------------------------------------------------------------
// Prep: ALL weight transposes (f32 -> bf16^T) fused into ONE dispatch.
// ---------------------------------------------------------------------------
__global__ __launch_bounds__(256)
void prep_weights(const float* __restrict__ Wq, const float* __restrict__ WaK,
                  const float* __restrict__ WaV, const float* __restrict__ WbK,
                  const float* __restrict__ WbV, const float* __restrict__ Wo,
                  const float* __restrict__ F1, const float* __restrict__ F2,
                  u16* __restrict__ WB1, u16* __restrict__ WbKT,
                  u16* __restrict__ WbVT, u16* __restrict__ WoT,
                  u16* __restrict__ F1T, u16* __restrict__ F2T)
{
  const int bid = blockIdx.x;
  const float* src; u16* dst; int R, C, tile, tilesX;
  if (bid < 1024)      { src = Wq;  dst = WB1;             R = 1024; C = 1024; tile = bid;        tilesX = 32; }
  else if (bid < 1280) { src = WaK; dst = WB1 + 1024*1024; R = 1024; C = 256;  tile = bid - 1024; tilesX = 8; }
  else if (bid < 1536) { src = WaV; dst = WB1 + 1280*1024; R = 1024; C = 256;  tile = bid - 1280; tilesX = 8; }
  else if (bid < 1792) { src = WbK; dst = WbKT;            R = 256;  C = 1024; tile = bid - 1536; tilesX = 32; }
  else if (bid < 2048) { src = WbV; dst = WbVT;            R = 256;  C = 1024; tile = bid - 1792; tilesX = 32; }
  else if (bid < 3072) { src = Wo;  dst = WoT;             R = 1024; C = 1024; tile = bid - 2048; tilesX = 32; }
  else if (bid < 7168) { src = F1;  dst = F1T;             R = 1024; C = 4096; tile = bid - 3072; tilesX = 128; }
  else                 { src = F2;  dst = F2T;             R = 4096; C = 1024; tile = bid - 7168; tilesX = 32; }
  const int bx = tile % tilesX, by = tile / tilesX;
  const int c0 = bx * 32, r0 = by * 32;

  __shared__ float tl[32][33];
  const int tx = threadIdx.x, ty = threadIdx.y;
#pragma unroll
  for (int i = 0; i < 4; ++i)
    tl[ty + i * 8][tx] = src[(size_t)(r0 + ty + i * 8) * C + c0 + tx];
  __syncthreads();
#pragma unroll
  for (int i = 0; i < 4; ++i)
    dst[(size_t)(c0 + ty + i * 8) * R + r0 + tx] = f2b(tl[tx][ty + i * 8]);
}

__global__ void cvt_f32_bf16(const float* __restrict__ in, u16* __restrict__ out, int n4)
{
  const int i = blockIdx.x * 256 + threadIdx.x;
  if (i >= n4) return;
  const float4 v = ((const float4*)in)[i];
  ushort4 o;
  o.x = f2b(v.x); o.y = f2b(v.y); o.z = f2b(v.z); o.w = f2b(v.w);
  ((ushort4*)out)[i] = o;
}

__global__ void concat_bias(const float* __restrict__ a, const float* __restrict__ b,
                            const float* __restrict__ c, float* __restrict__ o)
{
  const int i = blockIdx.x * 256 + threadIdx.x;
  if (i < 1024) o[i] = a[i];
  else if (i < 1280) o[i] = b[i - 1024];
  else if (i < 1536) o[i] = c[i - 1280];
}

// LN over (xa + y0 [+ y1]); NP = number of fp32 partials.
template<int WB, int NP>
__global__ __launch_bounds__(256)
void ln_kernel(const float* __restrict__ xa, const float* __restrict__ y0,
               const float* __restrict__ y1,
               const float* __restrict__ gam, const float* __restrict__ bet,
               float* __restrict__ outf, u16* __restrict__ outb)
{
  const int row = blockIdx.x, t = threadIdx.x;
  const float4 a = ((const float4*)(xa + (size_t)row * 1024))[t];
  const float4 c = ((const float4*)(y0 + (size_t)row * 1024))[t];
  float v0 = a.x + c.x, v1 = a.y + c.y, v2 = a.z + c.z, v3 = a.w + c.w;
  if constexpr (NP == 2) {
    const float4 d = ((const float4*)(y1 + (size_t)row * 1024))[t];
    v0 += d.x; v1 += d.y; v2 += d.z; v3 += d.w;
  }
  float s = v0 + v1 + v2 + v3;
  float q = v0 * v0 + v1 * v1 + v2 * v2 + v3 * v3;
#pragma unroll
  for (int off = 1; off < 64; off <<= 1) {
    s += __shfl_xor(s, off);
    q += __shfl_xor(q, off);
  }
  __shared__ float ss[4], qs[4];
  const int w = t >> 6, lane = t & 63;
  if (lane == 0) { ss[w] = s; qs[w] = q; }
  __syncthreads();
  const float S = ss[0] + ss[1] + ss[2] + ss[3];
  const float Q = qs[0] + qs[1] + qs[2] + qs[3];
  const float mean = S * (1.0f / 1024.0f);
  const float var = Q * (1.0f / 1024.0f) - mean * mean;
  const float rstd = rsqrtf(var + 1e-5f);
  const float4 gm = ((const float4*)gam)[t];
  const float4 bt = ((const float4*)bet)[t];
  const float o0 = (v0 - mean) * rstd * gm.x + bt.x;
  const float o1 = (v1 - mean) * rstd * gm.y + bt.y;
  const float o2 = (v2 - mean) * rstd * gm.z + bt.z;
  const float o3 = (v3 - mean) * rstd * gm.w + bt.w;
  float4 ov; ov.x = o0; ov.y = o1; ov.z = o2; ov.w = o3;
  ((float4*)(outf + (size_t)row * 1024))[t] = ov;
  if constexpr (WB) {
    ushort4 ob; ob.x = f2b(o0); ob.y = f2b(o1); ob.z = f2b(o2); ob.w = f2b(o3);
    ((ushort4*)(outb + (size_t)row * 1024))[t] = ob;
  }
}

// ---------------------------------------------------------------------------
extern "C" void kernel_launch(void* const* d_in, const int* in_sizes, int n_in,
                              void* d_out, int out_size, void* d_ws, size_t ws_size,
                              hipStream_t stream)
{
  const float* x     = (const float*)d_in[0];
  const float* abias = (const float*)d_in[1];
  const float* Wq_w  = (const float*)d_in[2];
  const float* Wq_b  = (const float*)d_in[3];
  const float* WaK_w = (const float*)d_in[4];
  const float* WaK_b = (const float*)d_in[5];
  const float* WbK_w = (const float*)d_in[6];
  const float* WbK_b = (const float*)d_in[7];
  const float* WaV_w = (const float*)d_in[8];
  const float* WaV_b = (const float*)d_in[9];
  const float* WbV_w = (const float*)d_in[10];
  const float* WbV_b = (const float*)d_in[11];
  const float* Wo_w  = (const float*)d_in[12];
  const float* Wo_b  = (const float*)d_in[13];
  const float* f1_w  = (const float*)d_in[14];
  const float* f1_b  = (const float*)d_in[15];
  const float* f2_w  = (const float*)d_in[16];
  const float* f2_b  = (const float*)d_in[17];
  const float* ln1_g = (const float*)d_in[18];
  const float* ln1_b = (const float*)d_in[19];
  const float* ln2_g = (const float*)d_in[20];
  const float* ln2_b = (const float*)d_in[21];

  char* ws = (char*)d_ws;
  u16*   xb    = (u16*)(ws + 0);          //  8 MB  x bf16 (dead after QKV gemm)
  u16*   WB1   = (u16*)(ws + 8388608);    //  3 MB
  u16*   WbKT  = (u16*)(ws + 11534336);   //  .5MB
  u16*   WbVT  = (u16*)(ws + 12058624);   //  .5MB
  u16*   WoT   = (u16*)(ws + 12582912);   //  2 MB (dead after O-proj)
  u16*   F1T   = (u16*)(ws + 14680064);   //  8 MB (dead after FFN1)
  u16*   F2T   = (u16*)(ws + 23068672);   //  8 MB
  float* bias1 = (float*)(ws + 31457280); //  6 KB
  u16*   G1    = (u16*)(ws + 39854080);   // 12 MB  [4096][1536] = Q|aK|aV
  u16*   Kb    = (u16*)(ws + 52436992);   //  8 MB
  u16*   Vt    = (u16*)(ws + 60825600);   //  8 MB
  u16*   Ob    = (u16*)(ws + 69214208);   //  8 MB
  float* Y     = (float*)(ws + 77602816); // 16 MB  fp32 partial 0
  float* x1f   = (float*)(ws + 94380032); // 16 MB
  u16*   x1b   = (u16*)(ws + 111157248);  //  8 MB
  u16*   hbuf  = G1;                      // 32 MB alias over G1..Ob (dead by FFN1)
  float* Y1    = (float*)(ws + 0);        // 16 MB partial 1 for FFN2 (aliases
                                          // xb..F1T head — all dead by FFN2)

  prep_weights<<<11264, dim3(32, 8), 0, stream>>>(Wq_w, WaK_w, WaV_w, WbK_w, WbV_w,
                                                  Wo_w, f1_w, f2_w,
                                                  WB1, WbKT, WbVT, WoT, F1T, F2T);
  cvt_f32_bf16<<<4096, 256, 0, stream>>>(x, xb, 1048576);
  concat_bias<<<6, 256, 0, stream>>>(Wq_b, WaK_b, WaV_b, bias1);

  // QKV-a projection: [4096,1024] x [1024,1536] -> Q | aK | aV
  gemm_bt<0, 128, 1><<<dim3(12, 32), 256, 0, stream>>>(xb, 1024, WB1, bias1, G1, nullptr, 1536, 4096, 1536, 1024);
  // K = aK @ WbK  (BN=64 -> 512 blocks)
  gemm_bt<0, 64, 1><<<dim3(16, 32), 256, 0, stream>>>(G1 + 1024, 1536, WbKT, WbK_b, Kb, nullptr, 1024, 4096, 1024, 256);
  // V = aV @ WbV, transposed store
  gemm_bt<3, 64, 1><<<dim3(16, 32), 256, 0, stream>>>(G1 + 1280, 1536, WbVT, WbV_b, Vt, nullptr, 2048, 4096, 1024, 256);
  // attention: 2048 blocks of 128 threads
  attn_kernel<<<dim3(32, 64), 128, 0, stream>>>(G1, Kb, Vt, abias, Ob);
  // O projection -> fp32 (BN=64 -> 512 blocks)
  gemm_bt<2, 64, 1><<<dim3(16, 32), 256, 0, stream>>>(Ob, 1024, WoT, Wo_b, Y, nullptr, 1024, 4096, 1024, 1024);
  // LN1(x + Y) -> x1 (fp32 + bf16)
  ln_kernel<1, 1><<<4096, 256, 0, stream>>>(x, Y, Y, ln1_g, ln1_b, x1f, x1b);
  // FFN1 + exact GELU -> h (bf16)
  gemm_bt<1, 128, 1><<<dim3(32, 32), 256, 0, stream>>>(x1b, 1024, F1T, f1_b, hbuf, nullptr, 4096, 4096, 4096, 1024);
  // FFN2 split-K=2 -> Y (z=0, +bias) and Y1 (z=1, explicit ptr)
  gemm_bt<2, 128, 2><<<dim3(8, 32, 2), 256, 0, stream>>>(hbuf, 4096, F2T, f2_b, Y, Y1, 1024, 4096, 1024, 4096);
  // LN2(x1 + Y + Y1) -> out
  ln_kernel<0, 2><<<4096, 256, 0, stream>>>(x1f, Y, Y1, ln2_g, ln2_b, (float*)d_out, nullptr);
}

// Round 6
// 418.224 us; speedup vs baseline: 1.0172x; 1.0172x over previous
//
#include <hip/hip_runtime.h>
#include <hip/hip_bf16.h>
#include <math.h>

typedef __attribute__((ext_vector_type(4))) float f32x4;
typedef __attribute__((ext_vector_type(8))) __bf16 bf16x8;
typedef unsigned short u16;

#define L2E 1.44269504088896f

__device__ __forceinline__ u16 f2b(float f) {
  union { float f; unsigned u; } x; x.f = f;
  unsigned r = x.u + 0x7fffu + ((x.u >> 16) & 1u);
  return (u16)(r >> 16);
}

__device__ __forceinline__ void gl_lds16(const void* g, void* l) {
  __builtin_amdgcn_global_load_lds(
      (const __attribute__((address_space(1))) void*)g,
      (__attribute__((address_space(3))) void*)l, 16, 0, 0);
}

// ---------------------------------------------------------------------------
// GEMM, T3 minimum-2-phase: double-buffered LDS, stage(t+1) issued BEFORE
// compute(t), ONE barrier per K-step (loads in flight under the MFMAs).
// C[M,N] = A[M,K] (bf16, lda) * Bt[N,K]^T (bf16) + bias[N]
// EPI: 0 = bf16, 1 = gelu+bf16, 2 = fp32, 3 = transposed V store
// SPLITK=2: z==0 -> C (+bias), z==1 -> C2 (explicit ptr, no bias)
// ---------------------------------------------------------------------------
template<int EPI, int BN, int SPLITK>
__global__ __launch_bounds__(256, 3)
void gemm_bt(const u16* __restrict__ A, int lda,
             const u16* __restrict__ Bt,
             const float* __restrict__ bias,
             void* __restrict__ C, void* __restrict__ C2, int ldc,
             int M, int N, int K)
{
  constexpr int NF = BN / 32;
  __shared__ u16 As[2][128 * 32];
  __shared__ u16 Bs[2][BN * 32];
  const int t = threadIdx.x;
  const int lane = t & 63;
  const int w = t >> 6;
  const int wr = w >> 1, wc = w & 1;
  const int row0 = blockIdx.y * 128, col0 = blockIdx.x * BN;
  const int r = lane & 15, g = lane >> 4;

  f32x4 acc[4][NF];
#pragma unroll
  for (int m = 0; m < 4; ++m)
#pragma unroll
    for (int n = 0; n < NF; ++n) acc[m][n] = (f32x4){0.f, 0.f, 0.f, 0.f};

  const int KS = K / SPLITK;
  const int kbeg = (SPLITK > 1) ? blockIdx.z * KS : 0;

  const u16* Ag = A + (size_t)(row0 + (t >> 2)) * lda + (t & 3) * 8 + kbeg;
  const u16* Bg = Bt + (size_t)(col0 + (t >> 2)) * K + (t & 3) * 8 + kbeg;
  const size_t a2 = (size_t)64 * lda, bo2 = (size_t)64 * K;
  const int si0 = t * 8, si1 = (t + 256) * 8;

  // prologue: stage K-step 0 into buffer 0
  gl_lds16(Ag, &As[0][si0]);
  gl_lds16(Ag + a2, &As[0][si1]);
  gl_lds16(Bg, &Bs[0][si0]);
  if constexpr (BN == 128) gl_lds16(Bg + bo2, &Bs[0][si1]);
  __syncthreads();

  int buf = 0;
  for (int kt = 0; kt < KS; kt += 32) {
    const int kn = kt + 32;
    if (kn < KS) {  // issue next-step stage FIRST (overlaps with MFMAs below)
      gl_lds16(Ag + kn, &As[buf ^ 1][si0]);
      gl_lds16(Ag + a2 + kn, &As[buf ^ 1][si1]);
      gl_lds16(Bg + kn, &Bs[buf ^ 1][si0]);
      if constexpr (BN == 128) gl_lds16(Bg + bo2 + kn, &Bs[buf ^ 1][si1]);
    }
    bf16x8 af[4], bfr[NF];
#pragma unroll
    for (int m = 0; m < 4; ++m)
      af[m] = *(const bf16x8*)&As[buf][(wr * 64 + m * 16 + r) * 32 + g * 8];
#pragma unroll
    for (int n = 0; n < NF; ++n)
      bfr[n] = *(const bf16x8*)&Bs[buf][(wc * (BN / 2) + n * 16 + r) * 32 + g * 8];
    __builtin_amdgcn_s_setprio(1);
#pragma unroll
    for (int m = 0; m < 4; ++m)
#pragma unroll
      for (int n = 0; n < NF; ++n)
        acc[m][n] = __builtin_amdgcn_mfma_f32_16x16x32_bf16(af[m], bfr[n], acc[m][n], 0, 0, 0);
    __builtin_amdgcn_s_setprio(0);
    __syncthreads();   // single barrier: reads of buf done + next stage landed
    buf ^= 1;
  }

  bool addb = true;
  float* Cf = (float*)C;
  if constexpr (SPLITK > 1) {
    if (blockIdx.z != 0) { addb = false; Cf = (float*)C2; }
  }

#pragma unroll
  for (int n = 0; n < NF; ++n) {
    const int col = col0 + wc * (BN / 2) + n * 16 + r;
    const float bv = addb ? bias[col] : 0.f;
#pragma unroll
    for (int m = 0; m < 4; ++m) {
      const int rb = row0 + wr * 64 + m * 16 + g * 4;
      if constexpr (EPI == 3) {
        const int b_ = rb >> 11, nn = rb & 2047;
        const int h_ = col >> 6, d_ = col & 63;
        u16* vp = (u16*)C + ((size_t)((b_ * 16 + h_) * 64 + d_)) * 2048 + nn;
        ushort4 pk;
        pk.x = f2b(acc[m][n][0] + bv);
        pk.y = f2b(acc[m][n][1] + bv);
        pk.z = f2b(acc[m][n][2] + bv);
        pk.w = f2b(acc[m][n][3] + bv);
        *(ushort4*)vp = pk;
      } else {
#pragma unroll
        for (int j = 0; j < 4; ++j) {
          float v = acc[m][n][j] + bv;
          if constexpr (EPI == 1) v = 0.5f * v * (1.0f + erff(v * 0.70710678118654752f));
          const size_t idx = (size_t)(rb + j) * ldc + col;
          if constexpr (EPI == 2) Cf[idx] = v;
          else ((u16*)C)[idx] = f2b(v);
        }
      }
    }
  }
}

// ---------------------------------------------------------------------------
// Flash attention: QBLK=64 (4 waves), KVBLK=64, DOUBLE-BUFFERED K/V with
// one barrier per tile (stage t+1 issued before compute t).
// Max-free softmax; Q pre-scaled 0.125*log2e; fp32 bias reg-prefetched.
// ---------------------------------------------------------------------------
__global__ __launch_bounds__(256, 4)
void attn_kernel(const u16* __restrict__ Qg,   // [4096][1536], cols 0..1023 = Q
                 const u16* __restrict__ Kg,   // [4096][1024]
                 const u16* __restrict__ Vt,   // [(b*16+h)*64+d][2048]
                 const float* __restrict__ Bf, // [2048][2048] fp32 bias
                 u16* __restrict__ O)          // [4096][1024]
{
  const int bh = blockIdx.x;
  const int b = bh >> 4, h = bh & 15;
  const int q0 = blockIdx.y * 64;
  const int t = threadIdx.x;
  const int lane = t & 63;
  const int w = t >> 6;
  const int r = lane & 15, g = lane >> 4;

  __shared__ u16 Ks[2][64 * 64];        // 16 KB
  __shared__ u16 Vs[2][64 * 64];        // 16 KB
  __shared__ __bf16 Ps[4][16 * 64];     //  8 KB

  bf16x8 qa[2];
  {
    const size_t qrow = (size_t)(b * 2048 + q0 + w * 16 + r);
    const u16* qp = Qg + qrow * 1536 + h * 64 + g * 8;
    qa[0] = *(const bf16x8*)qp;
    qa[1] = *(const bf16x8*)(qp + 32);
#pragma unroll
    for (int dh = 0; dh < 2; ++dh)
#pragma unroll
      for (int i = 0; i < 8; ++i)
        qa[dh][i] = (__bf16)((float)qa[dh][i] * (0.125f * L2E));
  }

  f32x4 Oa[4];
#pragma unroll
  for (int dc = 0; dc < 4; ++dc) Oa[dc] = (f32x4){0.f, 0.f, 0.f, 0.f};
  float lsum[4] = {0.f, 0.f, 0.f, 0.f};

  const int srow = t >> 3;
  const int spos = t & 7;
  const int sseg  = spos ^ (srow & 7);
  const int srow2 = srow + 32;
  const int sseg2 = spos ^ (srow2 & 7);
  const int si0 = t * 8, si1 = (t + 256) * 8;

  const u16* Kp0 = Kg + (size_t)(b * 2048 + srow)  * 1024 + h * 64 + sseg * 8;
  const u16* Kp1 = Kg + (size_t)(b * 2048 + srow2) * 1024 + h * 64 + sseg2 * 8;
  const u16* Vp0 = Vt + (size_t)(bh * 64 + srow)  * 2048 + sseg * 8;
  const u16* Vp1 = Vt + (size_t)(bh * 64 + srow2) * 2048 + sseg2 * 8;

  const float* bp = Bf + (size_t)(q0 + w * 16 + g * 4) * 2048 + r;

  // bias tile 0 prefetch (registers)
  float bn[4][4];
#pragma unroll
  for (int mc = 0; mc < 4; ++mc)
#pragma unroll
    for (int j = 0; j < 4; ++j)
      bn[mc][j] = bp[(size_t)j * 2048 + mc * 16];

  // prologue: stage tile 0 into buffer 0
  gl_lds16(Kp0, &Ks[0][si0]);
  gl_lds16(Kp1, &Ks[0][si1]);
  gl_lds16(Vp0, &Vs[0][si0]);
  gl_lds16(Vp1, &Vs[0][si1]);
  __syncthreads();

  int buf = 0;
  for (int mt = 0; mt < 32; ++mt) {
    const int m0 = mt * 64;
    if (mt < 31) {  // stage next tile first; lands under this tile's compute
      const int mn = m0 + 64;
      gl_lds16(Kp0 + (size_t)mn * 1024, &Ks[buf ^ 1][si0]);
      gl_lds16(Kp1 + (size_t)mn * 1024, &Ks[buf ^ 1][si1]);
      gl_lds16(Vp0 + mn, &Vs[buf ^ 1][si0]);
      gl_lds16(Vp1 + mn, &Vs[buf ^ 1][si1]);
    }

    f32x4 s[4];
#pragma unroll
    for (int mc = 0; mc < 4; ++mc)
#pragma unroll
      for (int j = 0; j < 4; ++j)
        s[mc][j] = bn[mc][j] * L2E;

    // S = log2e*(Q K^T / 8 + bias)
    __builtin_amdgcn_s_setprio(1);
#pragma unroll
    for (int mc = 0; mc < 4; ++mc) {
      const int mrow = mc * 16 + r;
      const bf16x8 kb0 = *(const bf16x8*)&Ks[buf][mrow * 64 + (((0 * 4 + g) ^ (mrow & 7)) * 8)];
      const bf16x8 kb1 = *(const bf16x8*)&Ks[buf][mrow * 64 + (((1 * 4 + g) ^ (mrow & 7)) * 8)];
      s[mc] = __builtin_amdgcn_mfma_f32_16x16x32_bf16(qa[0], kb0, s[mc], 0, 0, 0);
      s[mc] = __builtin_amdgcn_mfma_f32_16x16x32_bf16(qa[1], kb1, s[mc], 0, 0, 0);
    }
    __builtin_amdgcn_s_setprio(0);

    // next tile's bias (hidden under exp + PV)
    if (mt < 31) {
#pragma unroll
      for (int mc = 0; mc < 4; ++mc)
#pragma unroll
        for (int j = 0; j < 4; ++j)
          bn[mc][j] = bp[(size_t)j * 2048 + (m0 + 64) + mc * 16];
    }

    // p = 2^s; unnormalized row sums; P -> wave-local LDS (bf16)
    __bf16* pw = (__bf16*)Ps[w];
#pragma unroll
    for (int mc = 0; mc < 4; ++mc) {
      const int mm = mc * 16 + r;
#pragma unroll
      for (int j = 0; j < 4; ++j) {
        const float p = __builtin_amdgcn_exp2f(s[mc][j]);
        lsum[j] += p;
        const int qr = g * 4 + j;
        pw[qr * 64 + (((mm >> 3) ^ (qr & 7)) * 8) + (mm & 7)] = (__bf16)p;
      }
    }

    // PV: O += P * V
    const bf16x8 pa0 = *(const bf16x8*)&pw[r * 64 + (((0 * 4 + g) ^ (r & 7)) * 8)];
    const bf16x8 pa1 = *(const bf16x8*)&pw[r * 64 + (((1 * 4 + g) ^ (r & 7)) * 8)];
    __builtin_amdgcn_s_setprio(1);
#pragma unroll
    for (int dc = 0; dc < 4; ++dc) {
      const int drow = dc * 16 + r;
      const bf16x8 vb0 = *(const bf16x8*)&Vs[buf][drow * 64 + (((0 * 4 + g) ^ (drow & 7)) * 8)];
      const bf16x8 vb1 = *(const bf16x8*)&Vs[buf][drow * 64 + (((1 * 4 + g) ^ (drow & 7)) * 8)];
      Oa[dc] = __builtin_amdgcn_mfma_f32_16x16x32_bf16(pa0, vb0, Oa[dc], 0, 0, 0);
      Oa[dc] = __builtin_amdgcn_mfma_f32_16x16x32_bf16(pa1, vb1, Oa[dc], 0, 0, 0);
    }
    __builtin_amdgcn_s_setprio(0);
    __syncthreads();   // one barrier/tile: P+V reads done, next stage landed
    buf ^= 1;
  }

#pragma unroll
  for (int off = 1; off < 16; off <<= 1)
#pragma unroll
    for (int j = 0; j < 4; ++j) lsum[j] += __shfl_xor(lsum[j], off);

  u16* Os = Ks[0];
#pragma unroll
  for (int j = 0; j < 4; ++j) {
    const float inv = 1.0f / lsum[j];
    const int qr = w * 16 + g * 4 + j;
#pragma unroll
    for (int dc = 0; dc < 4; ++dc)
      Os[qr * 64 + dc * 16 + r] = f2b(Oa[dc][j] * inv);
  }
  __syncthreads();
#pragma unroll
  for (int i = 0; i < 2; ++i) {
    const int tt = t + i * 256;
    const int orow = tt >> 3, oseg = tt & 7;
    const uint4 v = *(const uint4*)&Os[orow * 64 + oseg * 8];
    *(uint4*)&O[(size_t)(b * 2048 + q0 + orow) * 1024 + h * 64 + oseg * 8] = v;
  }
}

// ---------------------------------------------------------------------------
// Prep: ALL weight transposes (f32 -> bf16^T) fused into ONE dispatch.
// ---------------------------------------------------------------------------
__global__ __launch_bounds__(256)
void prep_weights(const float* __restrict__ Wq, const float* __restrict__ WaK,
                  const float* __restrict__ WaV, const float* __restrict__ WbK,
                  const float* __restrict__ WbV, const float* __restrict__ Wo,
                  const float* __restrict__ F1, const float* __restrict__ F2,
                  u16* __restrict__ WB1, u16* __restrict__ WbKT,
                  u16* __restrict__ WbVT, u16* __restrict__ WoT,
                  u16* __restrict__ F1T, u16* __restrict__ F2T)
{
  const int bid = blockIdx.x;
  const float* src; u16* dst; int R, C, tile, tilesX;
  if (bid < 1024)      { src = Wq;  dst = WB1;             R = 1024; C = 1024; tile = bid;        tilesX = 32; }
  else if (bid < 1280) { src = WaK; dst = WB1 + 1024*1024; R = 1024; C = 256;  tile = bid - 1024; tilesX = 8; }
  else if (bid < 1536) { src = WaV; dst = WB1 + 1280*1024; R = 1024; C = 256;  tile = bid - 1280; tilesX = 8; }
  else if (bid < 1792) { src = WbK; dst = WbKT;            R = 256;  C = 1024; tile = bid - 1536; tilesX = 32; }
  else if (bid < 2048) { src = WbV; dst = WbVT;            R = 256;  C = 1024; tile = bid - 1792; tilesX = 32; }
  else if (bid < 3072) { src = Wo;  dst = WoT;             R = 1024; C = 1024; tile = bid - 2048; tilesX = 32; }
  else if (bid < 7168) { src = F1;  dst = F1T;             R = 1024; C = 4096; tile = bid - 3072; tilesX = 128; }
  else                 { src = F2;  dst = F2T;             R = 4096; C = 1024; tile = bid - 7168; tilesX = 32; }
  const int bx = tile % tilesX, by = tile / tilesX;
  const int c0 = bx * 32, r0 = by * 32;

  __shared__ float tl[32][33];
  const int tx = threadIdx.x, ty = threadIdx.y;
#pragma unroll
  for (int i = 0; i < 4; ++i)
    tl[ty + i * 8][tx] = src[(size_t)(r0 + ty + i * 8) * C + c0 + tx];
  __syncthreads();
#pragma unroll
  for (int i = 0; i < 4; ++i)
    dst[(size_t)(c0 + ty + i * 8) * R + r0 + tx] = f2b(tl[tx][ty + i * 8]);
}

__global__ void cvt_f32_bf16(const float* __restrict__ in, u16* __restrict__ out, int n4)
{
  const int i = blockIdx.x * 256 + threadIdx.x;
  if (i >= n4) return;
  const float4 v = ((const float4*)in)[i];
  ushort4 o;
  o.x = f2b(v.x); o.y = f2b(v.y); o.z = f2b(v.z); o.w = f2b(v.w);
  ((ushort4*)out)[i] = o;
}

__global__ void concat_bias(const float* __restrict__ a, const float* __restrict__ b,
                            const float* __restrict__ c, float* __restrict__ o)
{
  const int i = blockIdx.x * 256 + threadIdx.x;
  if (i < 1024) o[i] = a[i];
  else if (i < 1280) o[i] = b[i - 1024];
  else if (i < 1536) o[i] = c[i - 1280];
}

// LN over (xa + y0 [+ y1]); NP = number of fp32 partials.
template<int WB, int NP>
__global__ __launch_bounds__(256)
void ln_kernel(const float* __restrict__ xa, const float* __restrict__ y0,
               const float* __restrict__ y1,
               const float* __restrict__ gam, const float* __restrict__ bet,
               float* __restrict__ outf, u16* __restrict__ outb)
{
  const int row = blockIdx.x, t = threadIdx.x;
  const float4 a = ((const float4*)(xa + (size_t)row * 1024))[t];
  const float4 c = ((const float4*)(y0 + (size_t)row * 1024))[t];
  float v0 = a.x + c.x, v1 = a.y + c.y, v2 = a.z + c.z, v3 = a.w + c.w;
  if constexpr (NP == 2) {
    const float4 d = ((const float4*)(y1 + (size_t)row * 1024))[t];
    v0 += d.x; v1 += d.y; v2 += d.z; v3 += d.w;
  }
  float s = v0 + v1 + v2 + v3;
  float q = v0 * v0 + v1 * v1 + v2 * v2 + v3 * v3;
#pragma unroll
  for (int off = 1; off < 64; off <<= 1) {
    s += __shfl_xor(s, off);
    q += __shfl_xor(q, off);
  }
  __shared__ float ss[4], qs[4];
  const int w = t >> 6, lane = t & 63;
  if (lane == 0) { ss[w] = s; qs[w] = q; }
  __syncthreads();
  const float S = ss[0] + ss[1] + ss[2] + ss[3];
  const float Q = qs[0] + qs[1] + qs[2] + qs[3];
  const float mean = S * (1.0f / 1024.0f);
  const float var = Q * (1.0f / 1024.0f) - mean * mean;
  const float rstd = rsqrtf(var + 1e-5f);
  const float4 gm = ((const float4*)gam)[t];
  const float4 bt = ((const float4*)bet)[t];
  const float o0 = (v0 - mean) * rstd * gm.x + bt.x;
  const float o1 = (v1 - mean) * rstd * gm.y + bt.y;
  const float o2 = (v2 - mean) * rstd * gm.z + bt.z;
  const float o3 = (v3 - mean) * rstd * gm.w + bt.w;
  float4 ov; ov.x = o0; ov.y = o1; ov.z = o2; ov.w = o3;
  ((float4*)(outf + (size_t)row * 1024))[t] = ov;
  if constexpr (WB) {
    ushort4 ob; ob.x = f2b(o0); ob.y = f2b(o1); ob.z = f2b(o2); ob.w = f2b(o3);
    ((ushort4*)(outb + (size_t)row * 1024))[t] = ob;
  }
}

// ---------------------------------------------------------------------------
extern "C" void kernel_launch(void* const* d_in, const int* in_sizes, int n_in,
                              void* d_out, int out_size, void* d_ws, size_t ws_size,
                              hipStream_t stream)
{
  const float* x     = (const float*)d_in[0];
  const float* abias = (const float*)d_in[1];
  const float* Wq_w  = (const float*)d_in[2];
  const float* Wq_b  = (const float*)d_in[3];
  const float* WaK_w = (const float*)d_in[4];
  const float* WaK_b = (const float*)d_in[5];
  const float* WbK_w = (const float*)d_in[6];
  const float* WbK_b = (const float*)d_in[7];
  const float* WaV_w = (const float*)d_in[8];
  const float* WaV_b = (const float*)d_in[9];
  const float* WbV_w = (const float*)d_in[10];
  const float* WbV_b = (const float*)d_in[11];
  const float* Wo_w  = (const float*)d_in[12];
  const float* Wo_b  = (const float*)d_in[13];
  const float* f1_w  = (const float*)d_in[14];
  const float* f1_b  = (const float*)d_in[15];
  const float* f2_w  = (const float*)d_in[16];
  const float* f2_b  = (const float*)d_in[17];
  const float* ln1_g = (const float*)d_in[18];
  const float* ln1_b = (const float*)d_in[19];
  const float* ln2_g = (const float*)d_in[20];
  const float* ln2_b = (const float*)d_in[21];

  char* ws = (char*)d_ws;
  u16*   xb    = (u16*)(ws + 0);          //  8 MB  x bf16 (dead after QKV gemm)
  u16*   WB1   = (u16*)(ws + 8388608);    //  3 MB
  u16*   WbKT  = (u16*)(ws + 11534336);   //  .5MB
  u16*   WbVT  = (u16*)(ws + 12058624);   //  .5MB
  u16*   WoT   = (u16*)(ws + 12582912);   //  2 MB (dead after O-proj)
  u16*   F1T   = (u16*)(ws + 14680064);   //  8 MB (dead after FFN1)
  u16*   F2T   = (u16*)(ws + 23068672);   //  8 MB
  float* bias1 = (float*)(ws + 31457280); //  6 KB
  u16*   G1    = (u16*)(ws + 39854080);   // 12 MB  [4096][1536] = Q|aK|aV
  u16*   Kb    = (u16*)(ws + 52436992);   //  8 MB
  u16*   Vt    = (u16*)(ws + 60825600);   //  8 MB
  u16*   Ob    = (u16*)(ws + 69214208);   //  8 MB
  float* Y     = (float*)(ws + 77602816); // 16 MB  fp32 partial 0
  float* x1f   = (float*)(ws + 94380032); // 16 MB
  u16*   x1b   = (u16*)(ws + 111157248);  //  8 MB
  u16*   hbuf  = G1;                      // 32 MB alias over G1..Ob (dead by FFN1)
  float* Y1    = (float*)(ws + 0);        // 16 MB partial 1 for FFN2 (aliases
                                          // xb..F1T head — all dead by FFN2)

  prep_weights<<<11264, dim3(32, 8), 0, stream>>>(Wq_w, WaK_w, WaV_w, WbK_w, WbV_w,
                                                  Wo_w, f1_w, f2_w,
                                                  WB1, WbKT, WbVT, WoT, F1T, F2T);
  cvt_f32_bf16<<<4096, 256, 0, stream>>>(x, xb, 1048576);
  concat_bias<<<6, 256, 0, stream>>>(Wq_b, WaK_b, WaV_b, bias1);

  // QKV-a projection: [4096,1024] x [1024,1536] -> Q | aK | aV
  gemm_bt<0, 128, 1><<<dim3(12, 32), 256, 0, stream>>>(xb, 1024, WB1, bias1, G1, nullptr, 1536, 4096, 1536, 1024);
  // K = aK @ WbK  (BN=64 -> 512 blocks)
  gemm_bt<0, 64, 1><<<dim3(16, 32), 256, 0, stream>>>(G1 + 1024, 1536, WbKT, WbK_b, Kb, nullptr, 1024, 4096, 1024, 256);
  // V = aV @ WbV, transposed store
  gemm_bt<3, 64, 1><<<dim3(16, 32), 256, 0, stream>>>(G1 + 1280, 1536, WbVT, WbV_b, Vt, nullptr, 2048, 4096, 1024, 256);
  // attention: 1024 blocks of 256 threads, double-buffered
  attn_kernel<<<dim3(32, 32), 256, 0, stream>>>(G1, Kb, Vt, abias, Ob);
  // O projection -> fp32 (BN=64 -> 512 blocks)
  gemm_bt<2, 64, 1><<<dim3(16, 32), 256, 0, stream>>>(Ob, 1024, WoT, Wo_b, Y, nullptr, 1024, 4096, 1024, 1024);
  // LN1(x + Y) -> x1 (fp32 + bf16)
  ln_kernel<1, 1><<<4096, 256, 0, stream>>>(x, Y, Y, ln1_g, ln1_b, x1f, x1b);
  // FFN1 + exact GELU -> h (bf16)
  gemm_bt<1, 128, 1><<<dim3(32, 32), 256, 0, stream>>>(x1b, 1024, F1T, f1_b, hbuf, nullptr, 4096, 4096, 4096, 1024);
  // FFN2 split-K=2 -> Y (z=0, +bias) and Y1 (z=1, explicit ptr)
  gemm_bt<2, 128, 2><<<dim3(8, 32, 2), 256, 0, stream>>>(hbuf, 4096, F2T, f2_b, Y, Y1, 1024, 4096, 1024, 4096);
  // LN2(x1 + Y + Y1) -> out
  ln_kernel<0, 2><<<4096, 256, 0, stream>>>(x1f, Y, Y1, ln2_g, ln2_b, (float*)d_out, nullptr);
}